// Round 5
// baseline (397.115 us; speedup 1.0000x reference)
//
#include <hip/hip_runtime.h>

typedef unsigned short u16;

#define M_ROWS 8192
#define N_ROWS 16384
#define KDIM   512
#define KEXT   544                  /* 512 + 32-pad; k=512: nm_hi, k=513: nm_lo */
#define BM     256
#define BN     128
#define BK     32
#define NCHUNKS 16
#define NPER   (N_ROWS / NCHUNKS)   /* 1024 */
#define TOPK   9

#define ASZ (BM * BK)               /* 8192 u16 = 16 KB per A buffer */
#define BSZ (BN * BK)               /* 4096 u16 =  8 KB per B buffer */
#define KT  (KEXT / BK)             /* 17 */
#define NTT ((NPER / BN) * KT)      /* 8 nt * 17 kc = 136 tiles */

typedef __attribute__((ext_vector_type(8)))  short bf16x8;
typedef __attribute__((ext_vector_type(16))) float f32x16;

__device__ __forceinline__ void gload_lds16(const void* g, void* l) {
  __builtin_amdgcn_global_load_lds(
      (const __attribute__((address_space(1))) void*)g,
      (__attribute__((address_space(3))) void*)l,
      16, 0, 0);
}

__device__ __forceinline__ u16 f2bf(float x) {
  union { float f; unsigned u; } c; c.f = x;
  unsigned u = c.u;
  u += 0x7fffu + ((u >> 16) & 1u);   // RNE; inputs finite randn
  return (u16)(u >> 16);
}

__device__ __forceinline__ float bf2f(u16 x) {
  union { unsigned u; float f; } c; c.u = ((unsigned)x) << 16;
  return c.f;
}

// min-order insert (v-space distances; used by merge)
__device__ __forceinline__ void topk_update(float v, float* best) {
  if (v < best[TOPK - 1]) {
    #pragma unroll
    for (int i = 0; i < TOPK; ++i) {
      float b = best[i];
      best[i] = fminf(b, v);
      v = fmaxf(b, v);
    }
  }
}

// max-order insert (acc' = dot - nm/2 space; v = -2*acc' is monotone decreasing)
__device__ __forceinline__ void topk_update_max(float v, float* best) {
  if (v > best[TOPK - 1]) {
    #pragma unroll
    for (int i = 0; i < TOPK; ++i) {
      float b = best[i];
      best[i] = fmaxf(b, v);
      v = fminf(b, v);
    }
  }
}

// ---- Kernel 1: fp32 -> bf16 convert (rows padded to KEXT) + fp32 fv row norms.
// R5: nm is FOLDED into the GEMM: mb_ext[512] = -bf16(nm/2), mb_ext[513] =
// -bf16(nm/2 - hi) (two-term split, err ~2e-3), fv_ext[512..513] = 1.0.
// Then MFMA acc' = dot - nm/2 and ranked v = -2*acc' (monotone) -> the GEMM
// epilogue needs NO nm loads and NO fmafs, just a max-tree on raw acc.
__global__ __launch_bounds__(256) void prep_kernel(
    const float* __restrict__ fv, const float* __restrict__ mb,
    u16* __restrict__ fvb, u16* __restrict__ mbb, float* __restrict__ nf)
{
  int idx = blockIdx.x * 4 + (threadIdx.x >> 6);   // one wave per row
  int l = threadIdx.x & 63;
  const float* src; u16* dst;
  const bool isf = idx < M_ROWS;
  if (isf) {
    src = fv + (size_t)idx * KDIM; dst = fvb + (size_t)idx * KEXT;
  } else {
    int r = idx - M_ROWS;
    src = mb + (size_t)r * KDIM; dst = mbb + (size_t)r * KEXT;
  }
  float4 x0 = ((const float4*)src)[2 * l];
  float4 x1 = ((const float4*)src)[2 * l + 1];
  float s = x0.x * x0.x + x0.y * x0.y + x0.z * x0.z + x0.w * x0.w
          + x1.x * x1.x + x1.y * x1.y + x1.z * x1.z + x1.w * x1.w;
  uint4 o;
  o.x = (unsigned)f2bf(x0.x) | ((unsigned)f2bf(x0.y) << 16);
  o.y = (unsigned)f2bf(x0.z) | ((unsigned)f2bf(x0.w) << 16);
  o.z = (unsigned)f2bf(x1.x) | ((unsigned)f2bf(x1.y) << 16);
  o.w = (unsigned)f2bf(x1.z) | ((unsigned)f2bf(x1.w) << 16);
  ((uint4*)dst)[l] = o;
  #pragma unroll
  for (int off = 32; off > 0; off >>= 1) s += __shfl_xor(s, off, 64);
  // tail 32 u16 (k = 512..543): lanes 0..3 write one uint4 each
  if (l < 4) {
    uint4 z = {0u, 0u, 0u, 0u};
    if (l == 0) {
      unsigned e01;
      if (isf) {
        e01 = 0x3F80u | (0x3F80u << 16);                 // [1.0, 1.0]
      } else {
        float a = 0.5f * s;
        u16 ah = f2bf(a);
        u16 al = f2bf(a - bf2f(ah));
        e01 = (unsigned)(ah ^ 0x8000u) | ((unsigned)(al ^ 0x8000u) << 16);
      }
      z.x = e01;
    }
    ((uint4*)(dst + KDIM))[l] = z;
  }
  if (isf && l == 0) nf[idx] = s;
}

// ---- Kernel 2: bf16 32x32x16 MFMA GEMM (swapped operands) + per-thread top-9 ----
// grid (32, 16), block 256 (4 waves). Block: 256 fv-rows (m) x 1024 mb-rows (n).
// Structure = R3 (proven 219us): wave owns 64m-strip x 128n, acc[2][4]=128 AGPR,
// 3-buffer LDS ring, stage tt+2, counted vmcnt(6), one s_barrier/tile.
// R5 deltas: K extended to 544 (nm folded in, +6% MFMA), epilogue is max-order
// top-9 on RAW acc (no nm loads, no fmafs, C-row mapping irrelevant); -2x applied
// to the 9 values at write-out only. R2-R4 showed MfmaUtil+VALUBusy+LDS ~= 100%
// (issue-serialized at 2 waves/SIMD) -> cutting VALU insts is worth 1:1 time.
// Swizzle (BK=32, R3-proven): LDS chunk c of row r holds global chunk c^((r>>1)&3);
// staging pre-swizzles the per-lane SOURCE k-offset, frag reads XOR the chunk.
__global__ __launch_bounds__(256, 2) void gemm_topk_kernel(
    const u16* __restrict__ fvb, const u16* __restrict__ mbb,
    float* __restrict__ partial)
{
  extern __shared__ __align__(16) u16 sm[];
  u16* const Asm = sm;                 // 3 x [256][32] fv tiles, 48 KB
  u16* const Bsm = sm + 3 * ASZ;       // 3 x [128][32] mb tiles, 24 KB

  const int t   = threadIdx.x;
  const int l   = t & 63;
  const int w   = t >> 6;
  const int h   = l >> 5;        // half-wave: k-slice half
  const int c31 = l & 31;
  const int xr  = (c31 >> 1) & 3;      // read-side row swizzle bits

  const int m0    = blockIdx.x * BM;
  const int ncoff = blockIdx.y * NPER;

  // staging: lane l covers row (base + l>>2), chunk l&3; source chunk pre-swizzled
  const int srow = l >> 2;                           // 0..15
  const int sc   = ((l & 3) ^ ((l >> 3) & 3)) * 8;   // swizzled source k-off (u16)

  const u16* aSrc = fvb + (size_t)(m0 + w * 64 + srow) * KEXT + sc;
  const u16* bSrc = mbb + (size_t)(ncoff + w * 32 + srow) * KEXT + sc;

  // LDS frag-read offsets (u16 units)
  const int aRd  = (w * 64 + c31) * BK;
  const int bRd  = c31 * BK;
  const int ch0  = (h ^ xr) * 8;        // kk=0 chunk
  const int ch1  = ch0 ^ 16;            // kk=1 chunk

#define STAGE(koS_, nOffS_, bufS_) do {                                       \
    const u16* as_ = aSrc + (koS_) * BK;                                      \
    const u16* bs_ = bSrc + (nOffS_) + (koS_) * BK;                           \
    u16* ad_ = Asm + (bufS_) * ASZ + (w * 64) * BK;                           \
    u16* bd_ = Bsm + (bufS_) * BSZ + (w * 32) * BK;                           \
    gload_lds16(as_,             ad_);                                        \
    gload_lds16(as_ + 16 * KEXT, ad_ + 16 * BK);                              \
    gload_lds16(as_ + 32 * KEXT, ad_ + 32 * BK);                              \
    gload_lds16(as_ + 48 * KEXT, ad_ + 48 * BK);                              \
    gload_lds16(bs_,             bd_);                                        \
    gload_lds16(bs_ + 16 * KEXT, bd_ + 16 * BK);                              \
  } while (0)

  float best[2][TOPK];
  float T[2];
  #pragma unroll
  for (int s = 0; s < 2; ++s) {
    T[s] = -3.4e38f;
    #pragma unroll
    for (int i = 0; i < TOPK; ++i) best[s][i] = -3.4e38f;
  }

  f32x16 acc[2][4];

  // prologue: prime ring with tiles 0,1 (12 loads in flight), tile 0 resident
  STAGE(0, 0, 0);
  STAGE(1, 0, 1);
  asm volatile("s_waitcnt vmcnt(6)" ::: "memory");
  __builtin_amdgcn_s_barrier();

  int bC = 0, bS = 2;
  int ko = 0;                 // compute tile's k-index (0..16)
  int ko2 = 2;                // staging tile's k-index
  int nOff2 = 0;              // staging tile's B n-offset (u16)
  for (int tt = 0; tt < NTT; ++tt) {
    if (ko == 0) {
      #pragma unroll
      for (int s = 0; s < 2; ++s)
        #pragma unroll
        for (int i = 0; i < 4; ++i)
          #pragma unroll
          for (int r = 0; r < 16; ++r) acc[s][i][r] = 0.0f;
    }

    if (tt + 2 < NTT) STAGE(ko2, nOff2, bS);

    // ---- compute tile tt from buffer bC: 12 ds_read_b128, 16 MFMA ----
    {
      const u16* Ak = Asm + bC * ASZ;
      const u16* Bk = Bsm + bC * BSZ;
      {
        bf16x8 f0 = *(const bf16x8*)&Ak[aRd + ch0];
        bf16x8 f1 = *(const bf16x8*)&Ak[aRd + 1024 + ch0];
        #pragma unroll
        for (int i = 0; i < 4; ++i) {
          bf16x8 mbf = *(const bf16x8*)&Bk[bRd + i * 1024 + ch0];
          acc[0][i] = __builtin_amdgcn_mfma_f32_32x32x16_bf16(mbf, f0, acc[0][i], 0, 0, 0);
          acc[1][i] = __builtin_amdgcn_mfma_f32_32x32x16_bf16(mbf, f1, acc[1][i], 0, 0, 0);
        }
      }
      {
        bf16x8 f0 = *(const bf16x8*)&Ak[aRd + ch1];
        bf16x8 f1 = *(const bf16x8*)&Ak[aRd + 1024 + ch1];
        #pragma unroll
        for (int i = 0; i < 4; ++i) {
          bf16x8 mbf = *(const bf16x8*)&Bk[bRd + i * 1024 + ch1];
          acc[0][i] = __builtin_amdgcn_mfma_f32_32x32x16_bf16(mbf, f0, acc[0][i], 0, 0, 0);
          acc[1][i] = __builtin_amdgcn_mfma_f32_32x32x16_bf16(mbf, f1, acc[1][i], 0, 0, 0);
        }
      }
    }

    // ---- counted end-of-tile wait: tile tt+1 resident after this barrier ----
    if (tt < NTT - 1) {
      if (tt < NTT - 2) { asm volatile("s_waitcnt vmcnt(6)" ::: "memory"); }
      else              { asm volatile("s_waitcnt vmcnt(0)" ::: "memory"); }
      __builtin_amdgcn_s_barrier();
    }

    // ---- per-n-tile register epilogue: max-tree on raw acc, rare inserts ----
    if (ko == 16) {
      #pragma unroll
      for (int i = 0; i < 4; ++i) {
        #pragma unroll
        for (int s = 0; s < 2; ++s) {
          float bmax = acc[s][i][0];
          #pragma unroll
          for (int r = 1; r < 16; ++r) bmax = fmaxf(bmax, acc[s][i][r]);
          if (bmax > T[s]) {
            #pragma unroll
            for (int r = 0; r < 16; ++r) topk_update_max(acc[s][i][r], best[s]);
            T[s] = best[s][TOPK - 1];
          }
        }
      }
      #pragma unroll
      for (int s = 0; s < 2; ++s)
        T[s] = fmaxf(best[s][TOPK - 1], __shfl_xor(best[s][TOPK - 1], 32, 64));
    }

    bC = (bC == 2) ? 0 : bC + 1;
    bS = (bS == 2) ? 0 : bS + 1;
    ko = (ko == 16) ? 0 : ko + 1;
    if (ko2 == 16) { ko2 = 0; nOff2 += BN * KEXT; } else { ++ko2; }
  }

  // ---- merge the lane pair sharing each m-col; write v = -2*acc' ----
  #pragma unroll
  for (int s = 0; s < 2; ++s) {
    float tmp[TOPK];
    #pragma unroll
    for (int q = 0; q < TOPK; ++q) tmp[q] = __shfl_xor(best[s][q], 32, 64);
    #pragma unroll
    for (int q = 0; q < TOPK; ++q) topk_update_max(tmp[q], best[s]);
    int m = m0 + w * 64 + s * 32 + c31;
    size_t base = ((size_t)blockIdx.y * M_ROWS + m) * TOPK;
    if (h == 0) {
      #pragma unroll
      for (int q = 0; q < 5; ++q) partial[base + q] = -2.0f * best[s][q];
    } else {
      #pragma unroll
      for (int q = 5; q < TOPK; ++q) partial[base + q] = -2.0f * best[s][q];
    }
  }
}

// ---- Kernel 3 (fused merge+img): one block per image. Each thread merges the 16
// partial lists for 4 rows, writes pixel scores, block-argmax (first-max), then
// thread 0 re-merges the winning row and computes the softmax image score.
__global__ __launch_bounds__(256) void merge_img_kernel(
    const float* __restrict__ partial, const float* __restrict__ nf,
    const int* __restrict__ bptr, float* __restrict__ out_pix,
    float* __restrict__ out_img)
{
  const int img = blockIdx.x, t = threadIdx.x;
  __shared__ float sv[256];
  __shared__ int   si[256];
  float bv = -1.0f; int bi = 0;
  for (int k = 0; k < 4; ++k) {
    int p = t + k * 256;               // ascending per thread -> first-max ok
    int row = img * 1024 + p;
    float best[TOPK];
    #pragma unroll
    for (int i = 0; i < TOPK; ++i) best[i] = 3.4e38f;
    for (int s = 0; s < NCHUNKS; ++s) {
      const float* pp = &partial[((size_t)s * M_ROWS + row) * TOPK];
      #pragma unroll
      for (int i = 0; i < TOPK; ++i) topk_update(pp[i], best);
    }
    float d0 = sqrtf(fmaxf(best[0] + nf[row], 0.0f));
    out_pix[row] = d0;
    if (d0 > bv) { bv = d0; bi = p; }
  }
  sv[t] = bv; si[t] = bi;
  __syncthreads();
  for (int off = 128; off > 0; off >>= 1) {
    if (t < off) {
      float v2 = sv[t + off]; int i2 = si[t + off];
      if (v2 > sv[t] || (v2 == sv[t] && i2 < si[t])) { sv[t] = v2; si[t] = i2; }
    }
    __syncthreads();
  }
  if (t == 0) {
    int row = img * 1024 + si[0];
    float best[TOPK];
    #pragma unroll
    for (int i = 0; i < TOPK; ++i) best[i] = 3.4e38f;
    for (int s = 0; s < NCHUNKS; ++s) {
      const float* pp = &partial[((size_t)s * M_ROWS + row) * TOPK];
      #pragma unroll
      for (int i = 0; i < TOPK; ++i) topk_update(pp[i], best);
    }
    float nfr = nf[row];
    float d[TOPK];
    #pragma unroll
    for (int i = 0; i < TOPK; ++i) d[i] = sqrtf(fmaxf(best[i] + nfr, 0.0f));
    int b = bptr[0];
    float s0 = d[0];
    float score = s0;
    if (b > 1) {
      int bb = b < TOPK ? b : TOPK;
      float mx = s0;
      for (int i = 1; i < bb; ++i) mx = fmaxf(mx, d[i]);
      float den = 0.0f;
      for (int i = 0; i < bb; ++i) den += expf(d[i] - mx);
      score = s0 * (1.0f - expf(s0 - mx) / den);
    }
    out_img[img] = score;
  }
}

extern "C" void kernel_launch(void* const* d_in, const int* in_sizes, int n_in,
                              void* d_out, int out_size, void* d_ws, size_t ws_size,
                              hipStream_t stream) {
  const float* fv   = (const float*)d_in[0];
  const float* mb   = (const float*)d_in[1];
  const int*   bptr = (const int*)d_in[2];
  float* out = (float*)d_out;

  char* ws = (char*)d_ws;
  u16*   fvb     = (u16*)ws;                       // 8192*544*2  = 8912896 B
  u16*   mbb     = (u16*)(ws + 8912896);           // 16384*544*2 = 17825792 B
  float* nf      = (float*)(ws + 26738688);        // 32768 B
  float* partial = (float*)(ws + 26771456);        // 16*8192*9*4 = 4718592 B (end ~30.0 MB)

  hipLaunchKernelGGL(prep_kernel, dim3((M_ROWS + N_ROWS) / 4), dim3(256), 0, stream,
                     fv, mb, fvb, mbb, nf);
  hipLaunchKernelGGL(gemm_topk_kernel, dim3(M_ROWS / BM, NCHUNKS), dim3(256),
                     73728, stream, fvb, mbb, partial);
  hipLaunchKernelGGL(merge_img_kernel, dim3(8), dim3(256), 0, stream,
                     partial, nf, bptr, out, out + M_ROWS);
}

// Round 6
// 344.666 us; speedup vs baseline: 1.1522x; 1.1522x over previous
//
#include <hip/hip_runtime.h>

typedef unsigned short u16;

#define M_ROWS 8192
#define N_ROWS 16384
#define KDIM   512
#define BM     256
#define BN     256
#define BK     32
#define NCHUNKS 16
#define NPER   (N_ROWS / NCHUNKS)   /* 1024 */
#define TOPK   9

#define ASZ (BM * BK)               /* 8192 u16 = 16 KB per A buffer */
#define BSZ (BN * BK)               /* 8192 u16 = 16 KB per B buffer */
#define NTT ((NPER / BN) * (KDIM / BK))   /* 4 nt * 16 kc = 64 tiles */

typedef __attribute__((ext_vector_type(8)))  short bf16x8;
typedef __attribute__((ext_vector_type(16))) float f32x16;

__device__ __forceinline__ void gload_lds16(const void* g, void* l) {
  __builtin_amdgcn_global_load_lds(
      (const __attribute__((address_space(1))) void*)g,
      (__attribute__((address_space(3))) void*)l,
      16, 0, 0);
}

__device__ __forceinline__ u16 f2bf(float x) {
  union { float f; unsigned u; } c; c.f = x;
  unsigned u = c.u;
  u += 0x7fffu + ((u >> 16) & 1u);   // RNE; inputs finite randn
  return (u16)(u >> 16);
}

__device__ __forceinline__ void topk_update(float v, float* best) {
  if (v < best[TOPK - 1]) {
    #pragma unroll
    for (int i = 0; i < TOPK; ++i) {
      float b = best[i];
      best[i] = fminf(b, v);
      v = fmaxf(b, v);
    }
  }
}

// ---- Kernel 1: fp32 -> bf16 convert + fp32 row norms; mb norms scattered into
//      MFMA-C-layout permuted order so the GEMM epilogue reads them as broadcasts.
__global__ __launch_bounds__(256) void prep_kernel(
    const float* __restrict__ fv, const float* __restrict__ mb,
    u16* __restrict__ fvb, u16* __restrict__ mbb,
    float* __restrict__ nf, float* __restrict__ nm_perm)
{
  int idx = blockIdx.x * 4 + (threadIdx.x >> 6);   // one wave per row
  int l = threadIdx.x & 63;
  const float* src; u16* dst;
  if (idx < M_ROWS) {
    src = fv + (size_t)idx * KDIM; dst = fvb + (size_t)idx * KDIM;
  } else {
    int r = idx - M_ROWS;
    src = mb + (size_t)r * KDIM; dst = mbb + (size_t)r * KDIM;
  }
  float4 x0 = ((const float4*)src)[2 * l];
  float4 x1 = ((const float4*)src)[2 * l + 1];
  float s = x0.x * x0.x + x0.y * x0.y + x0.z * x0.z + x0.w * x0.w
          + x1.x * x1.x + x1.y * x1.y + x1.z * x1.z + x1.w * x1.w;
  uint4 o;
  o.x = (unsigned)f2bf(x0.x) | ((unsigned)f2bf(x0.y) << 16);
  o.y = (unsigned)f2bf(x0.z) | ((unsigned)f2bf(x0.w) << 16);
  o.z = (unsigned)f2bf(x1.x) | ((unsigned)f2bf(x1.y) << 16);
  o.w = (unsigned)f2bf(x1.z) | ((unsigned)f2bf(x1.w) << 16);
  ((uint4*)dst)[l] = o;
  #pragma unroll
  for (int off = 32; off > 0; off >>= 1) s += __shfl_down(s, off, 64);
  if (l == 0) {
    if (idx < M_ROWS) {
      nf[idx] = s;
    } else {
      // 32x32 C/D: within-tile row w5 = (r&3) + 8*(r>>2) + 4*h  ->  [tile][h][r]
      int n  = idx - M_ROWS;
      int ig = n >> 5;            // global 32-row tile index (512 tiles)
      int w5 = n & 31;
      int h  = (w5 >> 2) & 1;
      int r  = (w5 & 3) | ((w5 >> 3) << 2);
      nm_perm[(ig * 2 + h) * 16 + r] = s;
    }
  }
}

// ---- Kernel 2: bf16 32x32x16 MFMA GEMM (swapped operands) + per-thread top-9 ----
// R6: 256x256 block tile, 8 waves (512 thr). Per-wave body = R3's proven one
// (64m x 128n, acc[2][4] = 128 AGPR, 12 b128 reads / 16 MFMA / tile, ring-3,
// stage tt+2, counted vmcnt, one s_barrier per tile). Only block-level sharing
// changes: staged traffic drops M*N*K*2*(1/BM+1/BN): 1.71 -> 1.07 GB. R0/R3/R4/R5
// all plateaued at 7.8-8.9 TB/s staged => testing the L3/fabric-BW-bound theory.
// LDS 96 KB -> 1 block/CU, still 2 waves/SIMD. launch_bounds(512,2): 256-reg cap
// fits this body (R3 compiled to 100 VGPR + 128 AGPR); R1's spill was its fatter
// wave body (~270 regs), not the 8-wave shape.
// Swizzle (BK=32, R3-proven): LDS chunk c of row r holds global chunk c^((r>>1)&3);
// staging pre-swizzles the per-lane SOURCE k-offset, frag reads XOR the chunk.
__global__ __launch_bounds__(512, 2) void gemm_topk_kernel(
    const u16* __restrict__ fvb, const u16* __restrict__ mbb,
    const float* __restrict__ nm_perm, float* __restrict__ partial)
{
  extern __shared__ __align__(16) u16 sm[];
  u16* const Asm = sm;                 // 3 x [256][32] fv tiles, 48 KB
  u16* const Bsm = sm + 3 * ASZ;       // 3 x [256][32] mb tiles, 48 KB

  const int t   = threadIdx.x;
  const int l   = t & 63;
  const int w   = t >> 6;        // wave 0..7
  const int wm  = w >> 1;        // m-quarter (0..3): 64-wide m-strip
  const int wn  = w & 1;         // n-half (0..1): 128-wide n-strip
  const int h   = l >> 5;        // half-wave: k-slice half
  const int c31 = l & 31;
  const int xr  = (c31 >> 1) & 3;      // read-side row swizzle bits

  const int m0    = blockIdx.x * BM;
  const int ncoff = blockIdx.y * NPER;

  // staging: lane l covers row (base + l>>2), chunk l&3; source chunk pre-swizzled
  const int srow = l >> 2;                           // 0..15
  const int sc   = ((l & 3) ^ ((l >> 3) & 3)) * 8;   // swizzled source k-off (u16)

  // each wave stages 32 rows of A and 32 rows of B (2 gloads each)
  const u16* aSrc = fvb + (size_t)(m0 + w * 32 + srow) * KDIM + sc;
  const u16* bSrc = mbb + (size_t)(ncoff + w * 32 + srow) * KDIM + sc;

  // LDS frag-read offsets (u16 units)
  const int aRd  = (wm * 64 + c31) * BK;
  const int bRd  = (wn * 128 + c31) * BK;
  const int ch0  = (h ^ xr) * 8;        // kk=0 chunk
  const int ch1  = ch0 ^ 16;            // kk=1 chunk

#define STAGE(tt2_, bufS_) do {                                               \
    const size_t ao_ = (size_t)((tt2_) & 15) * BK;                            \
    const size_t bo_ = (size_t)((tt2_) >> 4) * ((size_t)BN * KDIM) + ao_;     \
    u16* ad_ = Asm + (bufS_) * ASZ + (w * 32) * BK;                           \
    u16* bd_ = Bsm + (bufS_) * BSZ + (w * 32) * BK;                           \
    gload_lds16(aSrc + ao_,             ad_);                                 \
    gload_lds16(aSrc + ao_ + 16 * KDIM, ad_ + 16 * BK);                       \
    gload_lds16(bSrc + bo_,             bd_);                                 \
    gload_lds16(bSrc + bo_ + 16 * KDIM, bd_ + 16 * BK);                       \
  } while (0)

  float best[2][TOPK];
  float T[2];
  #pragma unroll
  for (int s = 0; s < 2; ++s) {
    T[s] = 3.4e38f;
    #pragma unroll
    for (int i = 0; i < TOPK; ++i) best[s][i] = 3.4e38f;
  }

  f32x16 acc[2][4];

  // prologue: prime ring with tiles 0,1 (8 loads in flight), tile 0 resident
  STAGE(0, 0);
  STAGE(1, 1);
  asm volatile("s_waitcnt vmcnt(4)" ::: "memory");
  __builtin_amdgcn_s_barrier();

  int bC = 0, bS = 2;
  for (int tt = 0; tt < NTT; ++tt) {
    if ((tt & 15) == 0) {
      #pragma unroll
      for (int s = 0; s < 2; ++s)
        #pragma unroll
        for (int i = 0; i < 4; ++i)
          #pragma unroll
          for (int r = 0; r < 16; ++r) acc[s][i][r] = 0.0f;
    }

    if (tt + 2 < NTT) STAGE(tt + 2, bS);

    // ---- compute tile tt from buffer bC: 12 ds_read_b128, 16 MFMA ----
    {
      const u16* Ak = Asm + bC * ASZ;
      const u16* Bk = Bsm + bC * BSZ;
      {
        bf16x8 f0 = *(const bf16x8*)&Ak[aRd + ch0];
        bf16x8 f1 = *(const bf16x8*)&Ak[aRd + 32 * BK + ch0];
        #pragma unroll
        for (int i = 0; i < 4; ++i) {
          bf16x8 mbf = *(const bf16x8*)&Bk[bRd + i * 32 * BK + ch0];
          acc[0][i] = __builtin_amdgcn_mfma_f32_32x32x16_bf16(mbf, f0, acc[0][i], 0, 0, 0);
          acc[1][i] = __builtin_amdgcn_mfma_f32_32x32x16_bf16(mbf, f1, acc[1][i], 0, 0, 0);
        }
      }
      {
        bf16x8 f0 = *(const bf16x8*)&Ak[aRd + ch1];
        bf16x8 f1 = *(const bf16x8*)&Ak[aRd + 32 * BK + ch1];
        #pragma unroll
        for (int i = 0; i < 4; ++i) {
          bf16x8 mbf = *(const bf16x8*)&Bk[bRd + i * 32 * BK + ch1];
          acc[0][i] = __builtin_amdgcn_mfma_f32_32x32x16_bf16(mbf, f0, acc[0][i], 0, 0, 0);
          acc[1][i] = __builtin_amdgcn_mfma_f32_32x32x16_bf16(mbf, f1, acc[1][i], 0, 0, 0);
        }
      }
    }

    // ---- counted end-of-tile wait: tile tt+1 resident after this barrier ----
    if (tt < NTT - 1) {
      if (tt < NTT - 2) { asm volatile("s_waitcnt vmcnt(4)" ::: "memory"); }
      else              { asm volatile("s_waitcnt vmcnt(0)" ::: "memory"); }
      __builtin_amdgcn_s_barrier();
    }

    // ---- per-n-tile register epilogue (regs + global reads only) ----
    if ((tt & 15) == 15) {
      const int nt    = tt >> 4;
      const int nbase = ncoff + nt * BN;
      #pragma unroll
      for (int i = 0; i < 4; ++i) {
        const float4* np =
            (const float4*)&nm_perm[(((nbase >> 5) + wn * 4 + i) * 2 + h) * 16];
        float4 q0 = np[0], q1 = np[1], q2 = np[2], q3 = np[3];
        #pragma unroll
        for (int s = 0; s < 2; ++s) {
          float v[16];
          v[ 0] = fmaf(-2.0f, acc[s][i][ 0], q0.x);
          v[ 1] = fmaf(-2.0f, acc[s][i][ 1], q0.y);
          v[ 2] = fmaf(-2.0f, acc[s][i][ 2], q0.z);
          v[ 3] = fmaf(-2.0f, acc[s][i][ 3], q0.w);
          v[ 4] = fmaf(-2.0f, acc[s][i][ 4], q1.x);
          v[ 5] = fmaf(-2.0f, acc[s][i][ 5], q1.y);
          v[ 6] = fmaf(-2.0f, acc[s][i][ 6], q1.z);
          v[ 7] = fmaf(-2.0f, acc[s][i][ 7], q1.w);
          v[ 8] = fmaf(-2.0f, acc[s][i][ 8], q2.x);
          v[ 9] = fmaf(-2.0f, acc[s][i][ 9], q2.y);
          v[10] = fmaf(-2.0f, acc[s][i][10], q2.z);
          v[11] = fmaf(-2.0f, acc[s][i][11], q2.w);
          v[12] = fmaf(-2.0f, acc[s][i][12], q3.x);
          v[13] = fmaf(-2.0f, acc[s][i][13], q3.y);
          v[14] = fmaf(-2.0f, acc[s][i][14], q3.z);
          v[15] = fmaf(-2.0f, acc[s][i][15], q3.w);
          float bmin = 3.4e38f;
          #pragma unroll
          for (int r = 0; r < 16; ++r) bmin = fminf(bmin, v[r]);
          if (bmin < T[s]) {
            #pragma unroll
            for (int r = 0; r < 16; ++r) topk_update(v[r], best[s]);
            T[s] = best[s][TOPK - 1];
          }
        }
      }
      #pragma unroll
      for (int s = 0; s < 2; ++s)
        T[s] = fminf(best[s][TOPK - 1], __shfl_xor(best[s][TOPK - 1], 32, 64));
    }

    bC = (bC == 2) ? 0 : bC + 1;
    bS = (bS == 2) ? 0 : bS + 1;
  }

  // ---- merge the lane pair sharing each m-col (snapshot partner, insert) ----
  #pragma unroll
  for (int s = 0; s < 2; ++s) {
    float tmp[TOPK];
    #pragma unroll
    for (int q = 0; q < TOPK; ++q) tmp[q] = __shfl_xor(best[s][q], 32, 64);
    #pragma unroll
    for (int q = 0; q < TOPK; ++q) topk_update(tmp[q], best[s]);
  }

  // ---- cross-wave merge: wn=1 waves stash lists (LDS ring reused), wn=0 merge ----
  float* smerge = (float*)sm;          // 256 * 9 * 4 = 9216 B, fits in A-buf0
  __syncthreads();
  if (wn == 1 && h == 0) {
    #pragma unroll
    for (int s = 0; s < 2; ++s)
      #pragma unroll
      for (int q = 0; q < TOPK; ++q)
        smerge[(wm * 64 + s * 32 + c31) * TOPK + q] = best[s][q];
  }
  __syncthreads();
  if (wn == 0) {
    #pragma unroll
    for (int s = 0; s < 2; ++s) {
      const float* p = &smerge[(wm * 64 + s * 32 + c31) * TOPK];
      #pragma unroll
      for (int q = 0; q < TOPK; ++q) topk_update(p[q], best[s]);
      int m = m0 + wm * 64 + s * 32 + c31;
      size_t base = ((size_t)blockIdx.y * M_ROWS + m) * TOPK;
      if (h == 0) {
        #pragma unroll
        for (int q = 0; q < 5; ++q) partial[base + q] = best[s][q];
      } else {
        #pragma unroll
        for (int q = 5; q < TOPK; ++q) partial[base + q] = best[s][q];
      }
    }
  }
}

// ---------------- Kernel 3: merge 16 partial lists/row, sqrt, pixel scores ----------------
__global__ __launch_bounds__(256) void merge_kernel(
    const float* __restrict__ partial, const float* __restrict__ nf,
    float* __restrict__ final9, float* __restrict__ out_pix)
{
  int row = blockIdx.x * 256 + threadIdx.x;   // 8192 rows
  float best[TOPK];
  #pragma unroll
  for (int i = 0; i < TOPK; ++i) best[i] = 3.4e38f;
  for (int s = 0; s < NCHUNKS; ++s) {
    const float* p = &partial[((size_t)s * M_ROWS + row) * TOPK];
    #pragma unroll
    for (int i = 0; i < TOPK; ++i) topk_update(p[i], best);
  }
  float nfr = nf[row];
  float d[TOPK];
  #pragma unroll
  for (int i = 0; i < TOPK; ++i) d[i] = sqrtf(fmaxf(best[i] + nfr, 0.0f));
  out_pix[row] = d[0];
  #pragma unroll
  for (int i = 0; i < TOPK; ++i) final9[(size_t)row * TOPK + i] = d[i];
}

// ---------------- Kernel 4: per-image argmax (first-max) + softmax score ----------------
__global__ __launch_bounds__(256) void img_kernel(
    const float* __restrict__ out_pix, const float* __restrict__ final9,
    const int* __restrict__ bptr, float* __restrict__ out_img)
{
  int img = blockIdx.x, t = threadIdx.x;
  float bv = -1.0f; int bi = 0;
  for (int p = t; p < 1024; p += 256) {
    float v = out_pix[img * 1024 + p];
    if (v > bv) { bv = v; bi = p; }
  }
  __shared__ float sv[256];
  __shared__ int   si[256];
  sv[t] = bv; si[t] = bi;
  __syncthreads();
  for (int off = 128; off > 0; off >>= 1) {
    if (t < off) {
      float v2 = sv[t + off]; int i2 = si[t + off];
      if (v2 > sv[t] || (v2 == sv[t] && i2 < si[t])) { sv[t] = v2; si[t] = i2; }
    }
    __syncthreads();
  }
  if (t == 0) {
    int row = img * 1024 + si[0];
    int b = bptr[0];
    float s0 = final9[(size_t)row * TOPK + 0];
    float score = s0;
    if (b > 1) {
      int bb = b < TOPK ? b : TOPK;
      float mx = s0;
      for (int i = 1; i < bb; ++i) mx = fmaxf(mx, final9[(size_t)row * TOPK + i]);
      float den = 0.0f;
      for (int i = 0; i < bb; ++i) den += expf(final9[(size_t)row * TOPK + i] - mx);
      score = s0 * (1.0f - expf(s0 - mx) / den);
    }
    out_img[img] = score;
  }
}

extern "C" void kernel_launch(void* const* d_in, const int* in_sizes, int n_in,
                              void* d_out, int out_size, void* d_ws, size_t ws_size,
                              hipStream_t stream) {
  const float* fv   = (const float*)d_in[0];
  const float* mb   = (const float*)d_in[1];
  const int*   bptr = (const int*)d_in[2];
  float* out = (float*)d_out;

  char* ws = (char*)d_ws;
  u16*   fvb     = (u16*)ws;                       // 8388608 B
  u16*   mbb     = (u16*)(ws + 8388608);           // 16777216 B
  float* nf      = (float*)(ws + 25165824);        // 32768 B
  float* nm_perm = (float*)(ws + 25198592);        // 65536 B
  float* partial = (float*)(ws + 25264128);        // 16*8192*9*4 = 4718592 B
  float* final9  = (float*)(ws + 29982720);        // 294912 B   (end ~30.3 MB)

  hipLaunchKernelGGL(prep_kernel, dim3((M_ROWS + N_ROWS) / 4), dim3(256), 0, stream,
                     fv, mb, fvb, mbb, nf, nm_perm);
  hipLaunchKernelGGL(gemm_topk_kernel, dim3(M_ROWS / BM, NCHUNKS), dim3(512),
                     98304, stream, fvb, mbb, nm_perm, partial);
  hipLaunchKernelGGL(merge_kernel, dim3(M_ROWS / 256), dim3(256), 0, stream,
                     partial, nf, final9, out);
  hipLaunchKernelGGL(img_kernel, dim3(8), dim3(256), 0, stream,
                     out, final9, bptr, out + M_ROWS);
}

// Round 7
// 341.366 us; speedup vs baseline: 1.1633x; 1.0097x over previous
//
#include <hip/hip_runtime.h>

typedef unsigned short u16;

#define M_ROWS 8192
#define N_ROWS 16384
#define KDIM   512
#define BM     256
#define BN     256
#define BK     32
#define NCHUNKS 8
#define NPER   (N_ROWS / NCHUNKS)   /* 2048 */
#define TOPK   9

#define ASZ (BM * BK)               /* 8192 u16 = 16 KB per A buffer */
#define BSZ (BN * BK)               /* 8192 u16 = 16 KB per B buffer */
#define NTT ((NPER / BN) * (KDIM / BK))   /* 8 nt * 16 kc = 128 tiles */

typedef __attribute__((ext_vector_type(8)))  short bf16x8;
typedef __attribute__((ext_vector_type(16))) float f32x16;

__device__ __forceinline__ void gload_lds16(const void* g, void* l) {
  __builtin_amdgcn_global_load_lds(
      (const __attribute__((address_space(1))) void*)g,
      (__attribute__((address_space(3))) void*)l,
      16, 0, 0);
}

__device__ __forceinline__ u16 f2bf(float x) {
  union { float f; unsigned u; } c; c.f = x;
  unsigned u = c.u;
  u += 0x7fffu + ((u >> 16) & 1u);   // RNE; inputs finite randn
  return (u16)(u >> 16);
}

__device__ __forceinline__ void topk_update(float v, float* best) {
  if (v < best[TOPK - 1]) {
    #pragma unroll
    for (int i = 0; i < TOPK; ++i) {
      float b = best[i];
      best[i] = fminf(b, v);
      v = fmaxf(b, v);
    }
  }
}

// ---- Kernel 1: fp32 -> bf16 convert + fp32 row norms; mb norms scattered into
//      MFMA-C-layout permuted order so the GEMM epilogue reads them as broadcasts.
__global__ __launch_bounds__(256) void prep_kernel(
    const float* __restrict__ fv, const float* __restrict__ mb,
    u16* __restrict__ fvb, u16* __restrict__ mbb,
    float* __restrict__ nf, float* __restrict__ nm_perm)
{
  int idx = blockIdx.x * 4 + (threadIdx.x >> 6);   // one wave per row
  int l = threadIdx.x & 63;
  const float* src; u16* dst;
  if (idx < M_ROWS) {
    src = fv + (size_t)idx * KDIM; dst = fvb + (size_t)idx * KDIM;
  } else {
    int r = idx - M_ROWS;
    src = mb + (size_t)r * KDIM; dst = mbb + (size_t)r * KDIM;
  }
  float4 x0 = ((const float4*)src)[2 * l];
  float4 x1 = ((const float4*)src)[2 * l + 1];
  float s = x0.x * x0.x + x0.y * x0.y + x0.z * x0.z + x0.w * x0.w
          + x1.x * x1.x + x1.y * x1.y + x1.z * x1.z + x1.w * x1.w;
  uint4 o;
  o.x = (unsigned)f2bf(x0.x) | ((unsigned)f2bf(x0.y) << 16);
  o.y = (unsigned)f2bf(x0.z) | ((unsigned)f2bf(x0.w) << 16);
  o.z = (unsigned)f2bf(x1.x) | ((unsigned)f2bf(x1.y) << 16);
  o.w = (unsigned)f2bf(x1.z) | ((unsigned)f2bf(x1.w) << 16);
  ((uint4*)dst)[l] = o;
  #pragma unroll
  for (int off = 32; off > 0; off >>= 1) s += __shfl_down(s, off, 64);
  if (l == 0) {
    if (idx < M_ROWS) {
      nf[idx] = s;
    } else {
      // 32x32 C/D: within-tile row w5 = (r&3) + 8*(r>>2) + 4*h  ->  [tile][h][r]
      int n  = idx - M_ROWS;
      int ig = n >> 5;            // global 32-row tile index (512 tiles)
      int w5 = n & 31;
      int h  = (w5 >> 2) & 1;
      int r  = (w5 & 3) | ((w5 >> 3) << 2);
      nm_perm[(ig * 2 + h) * 16 + r] = s;
    }
  }
}

// ---- Kernel 2: bf16 32x32x16 MFMA GEMM (swapped operands) + per-thread top-9 ----
// R7: fine-phase schedule (T3+T4+T5) on R6's geometry. Evidence: R2/R3/R4/R6 all
// land at the m233 2-phase ceiling (~627 TF) regardless of tile/occupancy/ring ->
// structure-bound, not pipe-bound. Each BK32 tile = 2 template phases:
//   {6 ds_read (kk slice) || 2 stage-issues -> s_barrier -> lgkmcnt(0) ->
//    setprio(1) 8 MFMA setprio(0) -> s_barrier}
// counted vmcnt(4) only at tile end (never 0 mid-loop); ring-3 staging of tile
// tt+2 split A-half (phase 1) / B-half (phase 2). 8 waves 4m x 2n, wave owns
// 64m x 128n, acc[2][4] = 128 AGPR; per-phase reg peak ~200 < 256 -> no spill
// (R1's 8-phase failure was spill, not schedule). LDS 96 KB, grid (32,8) = 256
// blocks = exactly 1/CU. NCHUNKS 8 halves partial traffic.
// Swizzle (proven): LDS chunk c of row r holds global chunk c^((r>>1)&3); staging
// pre-swizzles the per-lane SOURCE k-offset, frag reads XOR the chunk.
__global__ __launch_bounds__(512, 2) void gemm_topk_kernel(
    const u16* __restrict__ fvb, const u16* __restrict__ mbb,
    const float* __restrict__ nm_perm, float* __restrict__ partial)
{
  extern __shared__ __align__(16) u16 sm[];
  u16* const Asm = sm;                 // 3 x [256][32] fv tiles, 48 KB
  u16* const Bsm = sm + 3 * ASZ;       // 3 x [256][32] mb tiles, 48 KB

  const int t   = threadIdx.x;
  const int l   = t & 63;
  const int w   = t >> 6;        // wave 0..7
  const int wm  = w >> 1;        // m-quarter (0..3): 64-wide m-strip
  const int wn  = w & 1;         // n-half (0..1): 128-wide n-strip
  const int h   = l >> 5;        // half-wave: k-octet half
  const int c31 = l & 31;
  const int xr  = (c31 >> 1) & 3;      // read-side row swizzle bits

  const int m0    = blockIdx.x * BM;
  const int ncoff = blockIdx.y * NPER;

  // staging: lane l covers row (base + l>>2), chunk l&3; source chunk pre-swizzled
  const int srow = l >> 2;                           // 0..15
  const int sc   = ((l & 3) ^ ((l >> 3) & 3)) * 8;   // swizzled source k-off (u16)

  // each wave stages 32 rows of A and 32 rows of B (2 gloads each)
  const u16* aSrc = fvb + (size_t)(m0 + w * 32 + srow) * KDIM + sc;
  const u16* bSrc = mbb + (size_t)(ncoff + w * 32 + srow) * KDIM + sc;

  // LDS frag-read offsets (u16 units)
  const int aRd  = (wm * 64 + c31) * BK;
  const int bRd  = (wn * 128 + c31) * BK;
  const int ch0  = (h ^ xr) * 8;        // kk=0 chunk
  const int ch1  = ch0 ^ 16;            // kk=1 chunk

#define STAGE_A(tt2_, bufS_) do {                                             \
    const size_t ao_ = (size_t)((tt2_) & 15) * BK;                            \
    u16* ad_ = Asm + (bufS_) * ASZ + (w * 32) * BK;                           \
    gload_lds16(aSrc + ao_,             ad_);                                 \
    gload_lds16(aSrc + ao_ + 16 * KDIM, ad_ + 16 * BK);                       \
  } while (0)
#define STAGE_B(tt2_, bufS_) do {                                             \
    const size_t bo_ = (size_t)((tt2_) >> 4) * ((size_t)BN * KDIM)            \
                     + (size_t)((tt2_) & 15) * BK;                            \
    u16* bd_ = Bsm + (bufS_) * BSZ + (w * 32) * BK;                           \
    gload_lds16(bSrc + bo_,             bd_);                                 \
    gload_lds16(bSrc + bo_ + 16 * KDIM, bd_ + 16 * BK);                       \
  } while (0)

  float best[2][TOPK];
  float T[2];
  #pragma unroll
  for (int s = 0; s < 2; ++s) {
    T[s] = 3.4e38f;
    #pragma unroll
    for (int i = 0; i < TOPK; ++i) best[s][i] = 3.4e38f;
  }

  f32x16 acc[2][4];

  // prologue: prime ring with tiles 0,1 (8 loads in flight), tile 0 resident
  STAGE_A(0, 0); STAGE_B(0, 0);
  STAGE_A(1, 1); STAGE_B(1, 1);
  asm volatile("s_waitcnt vmcnt(4)" ::: "memory");
  __builtin_amdgcn_s_barrier();

  int bC = 0, bS = 2;
  for (int tt = 0; tt < NTT; ++tt) {
    if ((tt & 15) == 0) {
      #pragma unroll
      for (int s = 0; s < 2; ++s)
        #pragma unroll
        for (int i = 0; i < 4; ++i)
          #pragma unroll
          for (int r = 0; r < 16; ++r) acc[s][i][r] = 0.0f;
    }

    const u16* Ak = Asm + bC * ASZ;
    const u16* Bk = Bsm + bC * BSZ;
    const bool doStage = (tt + 2 < NTT);

    // ================= phase 1: kk0 slice + A-half stage =================
    {
      bf16x8 f0 = *(const bf16x8*)&Ak[aRd + ch0];
      bf16x8 f1 = *(const bf16x8*)&Ak[aRd + 32 * BK + ch0];
      bf16x8 g0 = *(const bf16x8*)&Bk[bRd + 0 * 32 * BK + ch0];
      bf16x8 g1 = *(const bf16x8*)&Bk[bRd + 1 * 32 * BK + ch0];
      bf16x8 g2 = *(const bf16x8*)&Bk[bRd + 2 * 32 * BK + ch0];
      bf16x8 g3 = *(const bf16x8*)&Bk[bRd + 3 * 32 * BK + ch0];
      if (doStage) STAGE_A(tt + 2, bS);
      __builtin_amdgcn_s_barrier();
      asm volatile("s_waitcnt lgkmcnt(0)" ::: "memory");
      __builtin_amdgcn_s_setprio(1);
      acc[0][0] = __builtin_amdgcn_mfma_f32_32x32x16_bf16(g0, f0, acc[0][0], 0, 0, 0);
      acc[1][0] = __builtin_amdgcn_mfma_f32_32x32x16_bf16(g0, f1, acc[1][0], 0, 0, 0);
      acc[0][1] = __builtin_amdgcn_mfma_f32_32x32x16_bf16(g1, f0, acc[0][1], 0, 0, 0);
      acc[1][1] = __builtin_amdgcn_mfma_f32_32x32x16_bf16(g1, f1, acc[1][1], 0, 0, 0);
      acc[0][2] = __builtin_amdgcn_mfma_f32_32x32x16_bf16(g2, f0, acc[0][2], 0, 0, 0);
      acc[1][2] = __builtin_amdgcn_mfma_f32_32x32x16_bf16(g2, f1, acc[1][2], 0, 0, 0);
      acc[0][3] = __builtin_amdgcn_mfma_f32_32x32x16_bf16(g3, f0, acc[0][3], 0, 0, 0);
      acc[1][3] = __builtin_amdgcn_mfma_f32_32x32x16_bf16(g3, f1, acc[1][3], 0, 0, 0);
      __builtin_amdgcn_s_setprio(0);
      __builtin_amdgcn_s_barrier();
    }

    // ================= phase 2: kk1 slice + B-half stage =================
    {
      bf16x8 f0 = *(const bf16x8*)&Ak[aRd + ch1];
      bf16x8 f1 = *(const bf16x8*)&Ak[aRd + 32 * BK + ch1];
      bf16x8 g0 = *(const bf16x8*)&Bk[bRd + 0 * 32 * BK + ch1];
      bf16x8 g1 = *(const bf16x8*)&Bk[bRd + 1 * 32 * BK + ch1];
      bf16x8 g2 = *(const bf16x8*)&Bk[bRd + 2 * 32 * BK + ch1];
      bf16x8 g3 = *(const bf16x8*)&Bk[bRd + 3 * 32 * BK + ch1];
      if (doStage) STAGE_B(tt + 2, bS);
      __builtin_amdgcn_s_barrier();
      asm volatile("s_waitcnt lgkmcnt(0)" ::: "memory");
      __builtin_amdgcn_s_setprio(1);
      acc[0][0] = __builtin_amdgcn_mfma_f32_32x32x16_bf16(g0, f0, acc[0][0], 0, 0, 0);
      acc[1][0] = __builtin_amdgcn_mfma_f32_32x32x16_bf16(g0, f1, acc[1][0], 0, 0, 0);
      acc[0][1] = __builtin_amdgcn_mfma_f32_32x32x16_bf16(g1, f0, acc[0][1], 0, 0, 0);
      acc[1][1] = __builtin_amdgcn_mfma_f32_32x32x16_bf16(g1, f1, acc[1][1], 0, 0, 0);
      acc[0][2] = __builtin_amdgcn_mfma_f32_32x32x16_bf16(g2, f0, acc[0][2], 0, 0, 0);
      acc[1][2] = __builtin_amdgcn_mfma_f32_32x32x16_bf16(g2, f1, acc[1][2], 0, 0, 0);
      acc[0][3] = __builtin_amdgcn_mfma_f32_32x32x16_bf16(g3, f0, acc[0][3], 0, 0, 0);
      acc[1][3] = __builtin_amdgcn_mfma_f32_32x32x16_bf16(g3, f1, acc[1][3], 0, 0, 0);
      __builtin_amdgcn_s_setprio(0);
      // counted end-of-tile wait: tile tt+1 resident after this barrier;
      // tile tt+2's 4 loads stay in flight (never drain to 0 mid-loop).
      if (tt < NTT - 1) {
        if (tt < NTT - 2) { asm volatile("s_waitcnt vmcnt(4)" ::: "memory"); }
        else              { asm volatile("s_waitcnt vmcnt(0)" ::: "memory"); }
        __builtin_amdgcn_s_barrier();
      }
    }

    // ---- per-n-tile register epilogue (regs + global reads only) ----
    if ((tt & 15) == 15) {
      const int nt    = tt >> 4;
      const int nbase = ncoff + nt * BN;
      #pragma unroll
      for (int i = 0; i < 4; ++i) {
        const float4* np =
            (const float4*)&nm_perm[(((nbase >> 5) + wn * 4 + i) * 2 + h) * 16];
        float4 q0 = np[0], q1 = np[1], q2 = np[2], q3 = np[3];
        #pragma unroll
        for (int s = 0; s < 2; ++s) {
          float v[16];
          v[ 0] = fmaf(-2.0f, acc[s][i][ 0], q0.x);
          v[ 1] = fmaf(-2.0f, acc[s][i][ 1], q0.y);
          v[ 2] = fmaf(-2.0f, acc[s][i][ 2], q0.z);
          v[ 3] = fmaf(-2.0f, acc[s][i][ 3], q0.w);
          v[ 4] = fmaf(-2.0f, acc[s][i][ 4], q1.x);
          v[ 5] = fmaf(-2.0f, acc[s][i][ 5], q1.y);
          v[ 6] = fmaf(-2.0f, acc[s][i][ 6], q1.z);
          v[ 7] = fmaf(-2.0f, acc[s][i][ 7], q1.w);
          v[ 8] = fmaf(-2.0f, acc[s][i][ 8], q2.x);
          v[ 9] = fmaf(-2.0f, acc[s][i][ 9], q2.y);
          v[10] = fmaf(-2.0f, acc[s][i][10], q2.z);
          v[11] = fmaf(-2.0f, acc[s][i][11], q2.w);
          v[12] = fmaf(-2.0f, acc[s][i][12], q3.x);
          v[13] = fmaf(-2.0f, acc[s][i][13], q3.y);
          v[14] = fmaf(-2.0f, acc[s][i][14], q3.z);
          v[15] = fmaf(-2.0f, acc[s][i][15], q3.w);
          float bmin = 3.4e38f;
          #pragma unroll
          for (int r = 0; r < 16; ++r) bmin = fminf(bmin, v[r]);
          if (bmin < T[s]) {
            #pragma unroll
            for (int r = 0; r < 16; ++r) topk_update(v[r], best[s]);
            T[s] = best[s][TOPK - 1];
          }
        }
      }
      #pragma unroll
      for (int s = 0; s < 2; ++s)
        T[s] = fminf(best[s][TOPK - 1], __shfl_xor(best[s][TOPK - 1], 32, 64));
    }

    bC = (bC == 2) ? 0 : bC + 1;
    bS = (bS == 2) ? 0 : bS + 1;
  }

  // ---- merge the lane pair sharing each m-col (snapshot partner, insert) ----
  #pragma unroll
  for (int s = 0; s < 2; ++s) {
    float tmp[TOPK];
    #pragma unroll
    for (int q = 0; q < TOPK; ++q) tmp[q] = __shfl_xor(best[s][q], 32, 64);
    #pragma unroll
    for (int q = 0; q < TOPK; ++q) topk_update(tmp[q], best[s]);
  }

  // ---- cross-wave merge: wn=1 waves stash lists (LDS ring reused), wn=0 merge ----
  float* smerge = (float*)sm;          // 256 * 9 * 4 = 9216 B, fits in A-buf0
  __syncthreads();
  if (wn == 1 && h == 0) {
    #pragma unroll
    for (int s = 0; s < 2; ++s)
      #pragma unroll
      for (int q = 0; q < TOPK; ++q)
        smerge[(wm * 64 + s * 32 + c31) * TOPK + q] = best[s][q];
  }
  __syncthreads();
  if (wn == 0) {
    #pragma unroll
    for (int s = 0; s < 2; ++s) {
      const float* p = &smerge[(wm * 64 + s * 32 + c31) * TOPK];
      #pragma unroll
      for (int q = 0; q < TOPK; ++q) topk_update(p[q], best[s]);
      int m = m0 + wm * 64 + s * 32 + c31;
      size_t base = ((size_t)blockIdx.y * M_ROWS + m) * TOPK;
      if (h == 0) {
        #pragma unroll
        for (int q = 0; q < 5; ++q) partial[base + q] = best[s][q];
      } else {
        #pragma unroll
        for (int q = 5; q < TOPK; ++q) partial[base + q] = best[s][q];
      }
    }
  }
}

// ---------------- Kernel 3: merge 8 partial lists/row, sqrt, pixel scores ----------------
__global__ __launch_bounds__(256) void merge_kernel(
    const float* __restrict__ partial, const float* __restrict__ nf,
    float* __restrict__ final9, float* __restrict__ out_pix)
{
  int row = blockIdx.x * 256 + threadIdx.x;   // 8192 rows
  float best[TOPK];
  #pragma unroll
  for (int i = 0; i < TOPK; ++i) best[i] = 3.4e38f;
  for (int s = 0; s < NCHUNKS; ++s) {
    const float* p = &partial[((size_t)s * M_ROWS + row) * TOPK];
    #pragma unroll
    for (int i = 0; i < TOPK; ++i) topk_update(p[i], best);
  }
  float nfr = nf[row];
  float d[TOPK];
  #pragma unroll
  for (int i = 0; i < TOPK; ++i) d[i] = sqrtf(fmaxf(best[i] + nfr, 0.0f));
  out_pix[row] = d[0];
  #pragma unroll
  for (int i = 0; i < TOPK; ++i) final9[(size_t)row * TOPK + i] = d[i];
}

// ---------------- Kernel 4: per-image argmax (first-max) + softmax score ----------------
__global__ __launch_bounds__(256) void img_kernel(
    const float* __restrict__ out_pix, const float* __restrict__ final9,
    const int* __restrict__ bptr, float* __restrict__ out_img)
{
  int img = blockIdx.x, t = threadIdx.x;
  float bv = -1.0f; int bi = 0;
  for (int p = t; p < 1024; p += 256) {
    float v = out_pix[img * 1024 + p];
    if (v > bv) { bv = v; bi = p; }
  }
  __shared__ float sv[256];
  __shared__ int   si[256];
  sv[t] = bv; si[t] = bi;
  __syncthreads();
  for (int off = 128; off > 0; off >>= 1) {
    if (t < off) {
      float v2 = sv[t + off]; int i2 = si[t + off];
      if (v2 > sv[t] || (v2 == sv[t] && i2 < si[t])) { sv[t] = v2; si[t] = i2; }
    }
    __syncthreads();
  }
  if (t == 0) {
    int row = img * 1024 + si[0];
    int b = bptr[0];
    float s0 = final9[(size_t)row * TOPK + 0];
    float score = s0;
    if (b > 1) {
      int bb = b < TOPK ? b : TOPK;
      float mx = s0;
      for (int i = 1; i < bb; ++i) mx = fmaxf(mx, final9[(size_t)row * TOPK + i]);
      float den = 0.0f;
      for (int i = 0; i < bb; ++i) den += expf(final9[(size_t)row * TOPK + i] - mx);
      score = s0 * (1.0f - expf(s0 - mx) / den);
    }
    out_img[img] = score;
  }
}

extern "C" void kernel_launch(void* const* d_in, const int* in_sizes, int n_in,
                              void* d_out, int out_size, void* d_ws, size_t ws_size,
                              hipStream_t stream) {
  const float* fv   = (const float*)d_in[0];
  const float* mb   = (const float*)d_in[1];
  const int*   bptr = (const int*)d_in[2];
  float* out = (float*)d_out;

  char* ws = (char*)d_ws;
  u16*   fvb     = (u16*)ws;                       // 8388608 B
  u16*   mbb     = (u16*)(ws + 8388608);           // 16777216 B
  float* nf      = (float*)(ws + 25165824);        // 32768 B
  float* nm_perm = (float*)(ws + 25198592);        // 65536 B
  float* partial = (float*)(ws + 25264128);        // 8*8192*9*4 = 2359296 B
  float* final9  = (float*)(ws + 27623424);        // 294912 B   (end ~27.9 MB)

  hipLaunchKernelGGL(prep_kernel, dim3((M_ROWS + N_ROWS) / 4), dim3(256), 0, stream,
                     fv, mb, fvb, mbb, nf, nm_perm);
  hipLaunchKernelGGL(gemm_topk_kernel, dim3(M_ROWS / BM, NCHUNKS), dim3(512),
                     98304, stream, fvb, mbb, nm_perm, partial);
  hipLaunchKernelGGL(merge_kernel, dim3(M_ROWS / 256), dim3(256), 0, stream,
                     partial, nf, final9, out);
  hipLaunchKernelGGL(img_kernel, dim3(8), dim3(256), 0, stream,
                     out, final9, bptr, out + M_ROWS);
}

// Round 8
// 319.640 us; speedup vs baseline: 1.2424x; 1.0680x over previous
//
#include <hip/hip_runtime.h>

typedef unsigned short u16;

#define M_ROWS 8192
#define N_ROWS 16384
#define KDIM   512
#define BM     256
#define BN     128
#define BK     32
#define NCHUNKS 16
#define NPER   (N_ROWS / NCHUNKS)   /* 1024 */
#define TOPK   9

#define ASZ (BM * BK)               /* 8192 u16 = 16 KB per A buffer */
#define BSZ (BN * BK)               /* 4096 u16 =  8 KB per B buffer */
#define NTT ((NPER / BN) * (KDIM / BK))   /* 8 nt * 16 kc = 128 tiles */

typedef __attribute__((ext_vector_type(8)))  short bf16x8;
typedef __attribute__((ext_vector_type(16))) float f32x16;

__device__ __forceinline__ void gload_lds16(const void* g, void* l) {
  __builtin_amdgcn_global_load_lds(
      (const __attribute__((address_space(1))) void*)g,
      (__attribute__((address_space(3))) void*)l,
      16, 0, 0);
}

__device__ __forceinline__ u16 f2bf(float x) {
  union { float f; unsigned u; } c; c.f = x;
  unsigned u = c.u;
  u += 0x7fffu + ((u >> 16) & 1u);   // RNE; inputs finite randn
  return (u16)(u >> 16);
}

__device__ __forceinline__ void topk_update(float v, float* best) {
  if (v < best[TOPK - 1]) {
    #pragma unroll
    for (int i = 0; i < TOPK; ++i) {
      float b = best[i];
      best[i] = fminf(b, v);
      v = fmaxf(b, v);
    }
  }
}

// ---- Kernel 1: fp32 -> bf16 convert + fp32 row norms; mb norms scattered into
//      MFMA-C-layout permuted order so the GEMM epilogue reads them as broadcasts.
__global__ __launch_bounds__(256) void prep_kernel(
    const float* __restrict__ fv, const float* __restrict__ mb,
    u16* __restrict__ fvb, u16* __restrict__ mbb,
    float* __restrict__ nf, float* __restrict__ nm_perm)
{
  int idx = blockIdx.x * 4 + (threadIdx.x >> 6);   // one wave per row
  int l = threadIdx.x & 63;
  const float* src; u16* dst;
  if (idx < M_ROWS) {
    src = fv + (size_t)idx * KDIM; dst = fvb + (size_t)idx * KDIM;
  } else {
    int r = idx - M_ROWS;
    src = mb + (size_t)r * KDIM; dst = mbb + (size_t)r * KDIM;
  }
  float4 x0 = ((const float4*)src)[2 * l];
  float4 x1 = ((const float4*)src)[2 * l + 1];
  float s = x0.x * x0.x + x0.y * x0.y + x0.z * x0.z + x0.w * x0.w
          + x1.x * x1.x + x1.y * x1.y + x1.z * x1.z + x1.w * x1.w;
  uint4 o;
  o.x = (unsigned)f2bf(x0.x) | ((unsigned)f2bf(x0.y) << 16);
  o.y = (unsigned)f2bf(x0.z) | ((unsigned)f2bf(x0.w) << 16);
  o.z = (unsigned)f2bf(x1.x) | ((unsigned)f2bf(x1.y) << 16);
  o.w = (unsigned)f2bf(x1.z) | ((unsigned)f2bf(x1.w) << 16);
  ((uint4*)dst)[l] = o;
  #pragma unroll
  for (int off = 32; off > 0; off >>= 1) s += __shfl_down(s, off, 64);
  if (l == 0) {
    if (idx < M_ROWS) {
      nf[idx] = s;
    } else {
      // 32x32 C/D: within-tile row w5 = (r&3) + 8*(r>>2) + 4*h  ->  [tile][h][r]
      int n  = idx - M_ROWS;
      int ig = n >> 5;            // global 32-row tile index (512 tiles)
      int w5 = n & 31;
      int h  = (w5 >> 2) & 1;
      int r  = (w5 & 3) | ((w5 >> 3) << 2);
      nm_perm[(ig * 2 + h) * 16 + r] = s;
    }
  }
}

// ---- Kernel 2: bf16 32x32x16 MFMA GEMM (swapped operands) + per-thread top-9 ----
// R8 = R3 geometry x R7 schedule. Round-7 isolated two additive factors:
//  - fine-phase {ds_read || stage -> bar -> lgkm(0) -> setprio MFMA -> bar}: +8%
//    (R6 280 -> R7 257 at equal 1-block/CU residency)
//  - 2nd resident block/CU (cross-block wave overlap, m114): +22%
//    (R6 280 -> R3 219 at equal coarse schedule)
// R7's 256x256 tile (96 KB) could not have both; R3's BM256xBN128 BK32 ring-3
// (72 KB) fits 2 blocks/CU AND takes the R7 phase structure unchanged.
// Per tile: ph1 {6 ds_read kk0 || 4 A-gloads -> bar -> lgkm0 -> prio 8MFMA -> bar}
//           ph2 {6 ds_read kk1 || 2 B-gloads -> bar -> lgkm0 -> prio 8MFMA ->
//                vmcnt(6 counted, tile-end only) -> bar}
// grid (32,16) = 512 blocks = 2/CU; acc[2][4] = 128 AGPR + ~100 arch VGPR.
// Swizzle (proven): LDS chunk c of row r holds global chunk c^((r>>1)&3); staging
// pre-swizzles the per-lane SOURCE k-offset, frag reads XOR the chunk.
__global__ __launch_bounds__(256, 2) void gemm_topk_kernel(
    const u16* __restrict__ fvb, const u16* __restrict__ mbb,
    const float* __restrict__ nm_perm, float* __restrict__ partial)
{
  extern __shared__ __align__(16) u16 sm[];
  u16* const Asm = sm;                 // 3 x [256][32] fv tiles, 48 KB
  u16* const Bsm = sm + 3 * ASZ;       // 3 x [128][32] mb tiles, 24 KB

  const int t   = threadIdx.x;
  const int l   = t & 63;
  const int w   = t >> 6;
  const int h   = l >> 5;        // half-wave: k-slice half
  const int c31 = l & 31;
  const int xr  = (c31 >> 1) & 3;      // read-side row swizzle bits

  const int m0    = blockIdx.x * BM;
  const int ncoff = blockIdx.y * NPER;

  // staging: lane l covers row (base + l>>2), chunk l&3; source chunk pre-swizzled
  const int srow = l >> 2;                           // 0..15
  const int sc   = ((l & 3) ^ ((l >> 3) & 3)) * 8;   // swizzled source k-off (u16)

  const u16* aSrc = fvb + (size_t)(m0 + w * 64 + srow) * KDIM + sc;
  const u16* bSrc = mbb + (size_t)(ncoff + w * 32 + srow) * KDIM + sc;

  // LDS frag-read offsets (u16 units)
  const int aRd  = (w * 64 + c31) * BK;
  const int bRd  = c31 * BK;
  const int ch0  = (h ^ xr) * 8;        // kk=0 chunk
  const int ch1  = ch0 ^ 16;            // kk=1 chunk

#define STAGE_A(koS_, bufS_) do {                                             \
    const size_t ao_ = (size_t)(koS_) * BK;                                   \
    u16* ad_ = Asm + (bufS_) * ASZ + (w * 64) * BK;                           \
    gload_lds16(aSrc + ao_,             ad_);                                 \
    gload_lds16(aSrc + ao_ + 16 * KDIM, ad_ + 16 * BK);                       \
    gload_lds16(aSrc + ao_ + 32 * KDIM, ad_ + 32 * BK);                       \
    gload_lds16(aSrc + ao_ + 48 * KDIM, ad_ + 48 * BK);                       \
  } while (0)
#define STAGE_B(koS_, nOffS_, bufS_) do {                                     \
    const size_t bo_ = (size_t)(nOffS_) + (size_t)(koS_) * BK;                \
    u16* bd_ = Bsm + (bufS_) * BSZ + (w * 32) * BK;                           \
    gload_lds16(bSrc + bo_,             bd_);                                 \
    gload_lds16(bSrc + bo_ + 16 * KDIM, bd_ + 16 * BK);                       \
  } while (0)

  float best[2][TOPK];
  float T[2];
  #pragma unroll
  for (int s = 0; s < 2; ++s) {
    T[s] = 3.4e38f;
    #pragma unroll
    for (int i = 0; i < TOPK; ++i) best[s][i] = 3.4e38f;
  }

  f32x16 acc[2][4];

  // prologue: prime ring with tiles 0,1 (12 loads in flight), tile 0 resident
  STAGE_A(0, 0); STAGE_B(0, 0, 0);
  STAGE_A(1, 1); STAGE_B(1, 0, 1);
  asm volatile("s_waitcnt vmcnt(6)" ::: "memory");
  __builtin_amdgcn_s_barrier();

  int bC = 0, bS = 2;
  int ko2 = 2;                // staging tile's k-index (0..15)
  int nOff2 = 0;              // staging tile's B n-offset (u16)
  for (int tt = 0; tt < NTT; ++tt) {
    if ((tt & 15) == 0) {
      #pragma unroll
      for (int s = 0; s < 2; ++s)
        #pragma unroll
        for (int i = 0; i < 4; ++i)
          #pragma unroll
          for (int r = 0; r < 16; ++r) acc[s][i][r] = 0.0f;
    }

    const u16* Ak = Asm + bC * ASZ;
    const u16* Bk = Bsm + bC * BSZ;
    const bool doStage = (tt + 2 < NTT);

    // ================= phase 1: kk0 slice + A-half stage =================
    {
      bf16x8 f0 = *(const bf16x8*)&Ak[aRd + ch0];
      bf16x8 f1 = *(const bf16x8*)&Ak[aRd + 1024 + ch0];
      bf16x8 g0 = *(const bf16x8*)&Bk[bRd +    0 + ch0];
      bf16x8 g1 = *(const bf16x8*)&Bk[bRd + 1024 + ch0];
      bf16x8 g2 = *(const bf16x8*)&Bk[bRd + 2048 + ch0];
      bf16x8 g3 = *(const bf16x8*)&Bk[bRd + 3072 + ch0];
      if (doStage) STAGE_A(ko2, bS);
      __builtin_amdgcn_s_barrier();
      asm volatile("s_waitcnt lgkmcnt(0)" ::: "memory");
      __builtin_amdgcn_s_setprio(1);
      acc[0][0] = __builtin_amdgcn_mfma_f32_32x32x16_bf16(g0, f0, acc[0][0], 0, 0, 0);
      acc[1][0] = __builtin_amdgcn_mfma_f32_32x32x16_bf16(g0, f1, acc[1][0], 0, 0, 0);
      acc[0][1] = __builtin_amdgcn_mfma_f32_32x32x16_bf16(g1, f0, acc[0][1], 0, 0, 0);
      acc[1][1] = __builtin_amdgcn_mfma_f32_32x32x16_bf16(g1, f1, acc[1][1], 0, 0, 0);
      acc[0][2] = __builtin_amdgcn_mfma_f32_32x32x16_bf16(g2, f0, acc[0][2], 0, 0, 0);
      acc[1][2] = __builtin_amdgcn_mfma_f32_32x32x16_bf16(g2, f1, acc[1][2], 0, 0, 0);
      acc[0][3] = __builtin_amdgcn_mfma_f32_32x32x16_bf16(g3, f0, acc[0][3], 0, 0, 0);
      acc[1][3] = __builtin_amdgcn_mfma_f32_32x32x16_bf16(g3, f1, acc[1][3], 0, 0, 0);
      __builtin_amdgcn_s_setprio(0);
      __builtin_amdgcn_s_barrier();
    }

    // ================= phase 2: kk1 slice + B-half stage =================
    {
      bf16x8 f0 = *(const bf16x8*)&Ak[aRd + ch1];
      bf16x8 f1 = *(const bf16x8*)&Ak[aRd + 1024 + ch1];
      bf16x8 g0 = *(const bf16x8*)&Bk[bRd +    0 + ch1];
      bf16x8 g1 = *(const bf16x8*)&Bk[bRd + 1024 + ch1];
      bf16x8 g2 = *(const bf16x8*)&Bk[bRd + 2048 + ch1];
      bf16x8 g3 = *(const bf16x8*)&Bk[bRd + 3072 + ch1];
      if (doStage) STAGE_B(ko2, nOff2, bS);
      __builtin_amdgcn_s_barrier();
      asm volatile("s_waitcnt lgkmcnt(0)" ::: "memory");
      __builtin_amdgcn_s_setprio(1);
      acc[0][0] = __builtin_amdgcn_mfma_f32_32x32x16_bf16(g0, f0, acc[0][0], 0, 0, 0);
      acc[1][0] = __builtin_amdgcn_mfma_f32_32x32x16_bf16(g0, f1, acc[1][0], 0, 0, 0);
      acc[0][1] = __builtin_amdgcn_mfma_f32_32x32x16_bf16(g1, f0, acc[0][1], 0, 0, 0);
      acc[1][1] = __builtin_amdgcn_mfma_f32_32x32x16_bf16(g1, f1, acc[1][1], 0, 0, 0);
      acc[0][2] = __builtin_amdgcn_mfma_f32_32x32x16_bf16(g2, f0, acc[0][2], 0, 0, 0);
      acc[1][2] = __builtin_amdgcn_mfma_f32_32x32x16_bf16(g2, f1, acc[1][2], 0, 0, 0);
      acc[0][3] = __builtin_amdgcn_mfma_f32_32x32x16_bf16(g3, f0, acc[0][3], 0, 0, 0);
      acc[1][3] = __builtin_amdgcn_mfma_f32_32x32x16_bf16(g3, f1, acc[1][3], 0, 0, 0);
      __builtin_amdgcn_s_setprio(0);
      // counted end-of-tile wait: tile tt+1 resident after this barrier;
      // tile tt+2's 6 loads stay in flight (never drain to 0 mid-loop).
      if (tt < NTT - 1) {
        if (tt < NTT - 2) { asm volatile("s_waitcnt vmcnt(6)" ::: "memory"); }
        else              { asm volatile("s_waitcnt vmcnt(0)" ::: "memory"); }
        __builtin_amdgcn_s_barrier();
      }
    }

    // ---- per-n-tile register epilogue (regs + global reads only) ----
    if ((tt & 15) == 15) {
      const int nt    = tt >> 4;
      const int nbase = ncoff + nt * BN;
      #pragma unroll
      for (int i = 0; i < 4; ++i) {
        const float4* np = (const float4*)&nm_perm[(((nbase >> 5) + i) * 2 + h) * 16];
        float4 q0 = np[0], q1 = np[1], q2 = np[2], q3 = np[3];
        #pragma unroll
        for (int s = 0; s < 2; ++s) {
          float v[16];
          v[ 0] = fmaf(-2.0f, acc[s][i][ 0], q0.x);
          v[ 1] = fmaf(-2.0f, acc[s][i][ 1], q0.y);
          v[ 2] = fmaf(-2.0f, acc[s][i][ 2], q0.z);
          v[ 3] = fmaf(-2.0f, acc[s][i][ 3], q0.w);
          v[ 4] = fmaf(-2.0f, acc[s][i][ 4], q1.x);
          v[ 5] = fmaf(-2.0f, acc[s][i][ 5], q1.y);
          v[ 6] = fmaf(-2.0f, acc[s][i][ 6], q1.z);
          v[ 7] = fmaf(-2.0f, acc[s][i][ 7], q1.w);
          v[ 8] = fmaf(-2.0f, acc[s][i][ 8], q2.x);
          v[ 9] = fmaf(-2.0f, acc[s][i][ 9], q2.y);
          v[10] = fmaf(-2.0f, acc[s][i][10], q2.z);
          v[11] = fmaf(-2.0f, acc[s][i][11], q2.w);
          v[12] = fmaf(-2.0f, acc[s][i][12], q3.x);
          v[13] = fmaf(-2.0f, acc[s][i][13], q3.y);
          v[14] = fmaf(-2.0f, acc[s][i][14], q3.z);
          v[15] = fmaf(-2.0f, acc[s][i][15], q3.w);
          float bmin = 3.4e38f;
          #pragma unroll
          for (int r = 0; r < 16; ++r) bmin = fminf(bmin, v[r]);
          if (bmin < T[s]) {
            #pragma unroll
            for (int r = 0; r < 16; ++r) topk_update(v[r], best[s]);
            T[s] = best[s][TOPK - 1];
          }
        }
      }
      #pragma unroll
      for (int s = 0; s < 2; ++s)
        T[s] = fminf(best[s][TOPK - 1], __shfl_xor(best[s][TOPK - 1], 32, 64));
    }

    bC = (bC == 2) ? 0 : bC + 1;
    bS = (bS == 2) ? 0 : bS + 1;
    if (ko2 == 15) { ko2 = 0; nOff2 += BN * KDIM; } else { ++ko2; }
  }

  // merge the lane pair sharing each m-col (snapshot partner list, then insert)
  #pragma unroll
  for (int s = 0; s < 2; ++s) {
    float tmp[TOPK];
    #pragma unroll
    for (int q = 0; q < TOPK; ++q) tmp[q] = __shfl_xor(best[s][q], 32, 64);
    #pragma unroll
    for (int q = 0; q < TOPK; ++q) topk_update(tmp[q], best[s]);
    int m = m0 + w * 64 + s * 32 + c31;
    size_t base = ((size_t)blockIdx.y * M_ROWS + m) * TOPK;
    if (h == 0) {
      #pragma unroll
      for (int q = 0; q < 5; ++q) partial[base + q] = best[s][q];
    } else {
      #pragma unroll
      for (int q = 5; q < TOPK; ++q) partial[base + q] = best[s][q];
    }
  }
}

// ---------------- Kernel 3: merge 16 partial lists/row, sqrt, pixel scores ----------------
__global__ __launch_bounds__(256) void merge_kernel(
    const float* __restrict__ partial, const float* __restrict__ nf,
    float* __restrict__ final9, float* __restrict__ out_pix)
{
  int row = blockIdx.x * 256 + threadIdx.x;   // 8192 rows
  float best[TOPK];
  #pragma unroll
  for (int i = 0; i < TOPK; ++i) best[i] = 3.4e38f;
  for (int s = 0; s < NCHUNKS; ++s) {
    const float* p = &partial[((size_t)s * M_ROWS + row) * TOPK];
    #pragma unroll
    for (int i = 0; i < TOPK; ++i) topk_update(p[i], best);
  }
  float nfr = nf[row];
  float d[TOPK];
  #pragma unroll
  for (int i = 0; i < TOPK; ++i) d[i] = sqrtf(fmaxf(best[i] + nfr, 0.0f));
  out_pix[row] = d[0];
  #pragma unroll
  for (int i = 0; i < TOPK; ++i) final9[(size_t)row * TOPK + i] = d[i];
}

// ---------------- Kernel 4: per-image argmax (first-max) + softmax score ----------------
__global__ __launch_bounds__(256) void img_kernel(
    const float* __restrict__ out_pix, const float* __restrict__ final9,
    const int* __restrict__ bptr, float* __restrict__ out_img)
{
  int img = blockIdx.x, t = threadIdx.x;
  float bv = -1.0f; int bi = 0;
  for (int p = t; p < 1024; p += 256) {
    float v = out_pix[img * 1024 + p];
    if (v > bv) { bv = v; bi = p; }
  }
  __shared__ float sv[256];
  __shared__ int   si[256];
  sv[t] = bv; si[t] = bi;
  __syncthreads();
  for (int off = 128; off > 0; off >>= 1) {
    if (t < off) {
      float v2 = sv[t + off]; int i2 = si[t + off];
      if (v2 > sv[t] || (v2 == sv[t] && i2 < si[t])) { sv[t] = v2; si[t] = i2; }
    }
    __syncthreads();
  }
  if (t == 0) {
    int row = img * 1024 + si[0];
    int b = bptr[0];
    float s0 = final9[(size_t)row * TOPK + 0];
    float score = s0;
    if (b > 1) {
      int bb = b < TOPK ? b : TOPK;
      float mx = s0;
      for (int i = 1; i < bb; ++i) mx = fmaxf(mx, final9[(size_t)row * TOPK + i]);
      float den = 0.0f;
      for (int i = 0; i < bb; ++i) den += expf(final9[(size_t)row * TOPK + i] - mx);
      score = s0 * (1.0f - expf(s0 - mx) / den);
    }
    out_img[img] = score;
  }
}

extern "C" void kernel_launch(void* const* d_in, const int* in_sizes, int n_in,
                              void* d_out, int out_size, void* d_ws, size_t ws_size,
                              hipStream_t stream) {
  const float* fv   = (const float*)d_in[0];
  const float* mb   = (const float*)d_in[1];
  const int*   bptr = (const int*)d_in[2];
  float* out = (float*)d_out;

  char* ws = (char*)d_ws;
  u16*   fvb     = (u16*)ws;                       // 8388608 B
  u16*   mbb     = (u16*)(ws + 8388608);           // 16777216 B
  float* nf      = (float*)(ws + 25165824);        // 32768 B
  float* nm_perm = (float*)(ws + 25198592);        // 65536 B
  float* partial = (float*)(ws + 25264128);        // 16*8192*9*4 = 4718592 B
  float* final9  = (float*)(ws + 29982720);        // 294912 B   (end ~30.3 MB)

  hipLaunchKernelGGL(prep_kernel, dim3((M_ROWS + N_ROWS) / 4), dim3(256), 0, stream,
                     fv, mb, fvb, mbb, nf, nm_perm);
  hipLaunchKernelGGL(gemm_topk_kernel, dim3(M_ROWS / BM, NCHUNKS), dim3(256),
                     73728, stream, fvb, mbb, nm_perm, partial);
  hipLaunchKernelGGL(merge_kernel, dim3(M_ROWS / 256), dim3(256), 0, stream,
                     partial, nf, final9, out);
  hipLaunchKernelGGL(img_kernel, dim3(8), dim3(256), 0, stream,
                     out, final9, bptr, out + M_ROWS);
}

// Round 9
// 292.100 us; speedup vs baseline: 1.3595x; 1.0943x over previous
//
#include <hip/hip_runtime.h>

typedef unsigned short u16;

#define M_ROWS 8192
#define N_ROWS 16384
#define KDIM   512
#define BM     256
#define BN     128
#define BK     64
#define NCHUNKS 16
#define NPER   (N_ROWS / NCHUNKS)   /* 1024 */
#define TOPK   9

typedef __attribute__((ext_vector_type(8)))  short bf16x8;
typedef __attribute__((ext_vector_type(16))) float f32x16;

__device__ __forceinline__ void gload_lds16(const void* g, void* l) {
  __builtin_amdgcn_global_load_lds(
      (const __attribute__((address_space(1))) void*)g,
      (__attribute__((address_space(3))) void*)l,
      16, 0, 0);
}

__device__ __forceinline__ u16 f2bf(float x) {
  union { float f; unsigned u; } c; c.f = x;
  unsigned u = c.u;
  u += 0x7fffu + ((u >> 16) & 1u);   // RNE; inputs finite randn
  return (u16)(u >> 16);
}

__device__ __forceinline__ void topk_update(float v, float* best) {
  if (v < best[TOPK - 1]) {
    #pragma unroll
    for (int i = 0; i < TOPK; ++i) {
      float b = best[i];
      best[i] = fminf(b, v);
      v = fmaxf(b, v);
    }
  }
}

// ---- Kernel 1: fp32 -> bf16 convert + fp32 row norms; mb norms scattered into
//      MFMA-C-layout permuted order so the GEMM epilogue reads them as broadcasts.
__global__ __launch_bounds__(256) void prep_kernel(
    const float* __restrict__ fv, const float* __restrict__ mb,
    u16* __restrict__ fvb, u16* __restrict__ mbb,
    float* __restrict__ nf, float* __restrict__ nm_perm)
{
  int idx = blockIdx.x * 4 + (threadIdx.x >> 6);   // one wave per row
  int l = threadIdx.x & 63;
  const float* src; u16* dst;
  if (idx < M_ROWS) {
    src = fv + (size_t)idx * KDIM; dst = fvb + (size_t)idx * KDIM;
  } else {
    int r = idx - M_ROWS;
    src = mb + (size_t)r * KDIM; dst = mbb + (size_t)r * KDIM;
  }
  float4 x0 = ((const float4*)src)[2 * l];
  float4 x1 = ((const float4*)src)[2 * l + 1];
  float s = x0.x * x0.x + x0.y * x0.y + x0.z * x0.z + x0.w * x0.w
          + x1.x * x1.x + x1.y * x1.y + x1.z * x1.z + x1.w * x1.w;
  uint4 o;
  o.x = (unsigned)f2bf(x0.x) | ((unsigned)f2bf(x0.y) << 16);
  o.y = (unsigned)f2bf(x0.z) | ((unsigned)f2bf(x0.w) << 16);
  o.z = (unsigned)f2bf(x1.x) | ((unsigned)f2bf(x1.y) << 16);
  o.w = (unsigned)f2bf(x1.z) | ((unsigned)f2bf(x1.w) << 16);
  ((uint4*)dst)[l] = o;
  #pragma unroll
  for (int off = 32; off > 0; off >>= 1) s += __shfl_down(s, off, 64);
  if (l == 0) {
    if (idx < M_ROWS) {
      nf[idx] = s;
    } else {
      // 32x32 C/D: within-tile row w5 = (r&3) + 8*(r>>2) + 4*h  ->  [tile][h][r]
      int n  = idx - M_ROWS;
      int ig = n >> 5;            // global 32-row tile index (512 tiles)
      int w5 = n & 31;
      int h  = (w5 >> 2) & 1;
      int r  = (w5 & 3) | ((w5 >> 3) << 2);
      nm_perm[(ig * 2 + h) * 16 + r] = s;
    }
  }
}

// ---- Kernel 2: bf16 32x32x16 MFMA GEMM (swapped operands) + per-thread top-9 ----
// grid (32, 16), block 256 (4 waves). Block: 256 fv-rows (m) x 1024 mb-rows (n).
// Wave owns a 64-wide m-strip (2 x 32 sub-strips): per kk 2 fvf + 4 mbf
// ds_read_b128 feed 8 MFMAs = 0.75 reads/MFMA. acc[2][4] = 128 AGPR.
// PLATEAU NOTE (R0-R8): 8 schedule variants (coarse/counted-vmcnt/fine-phase x
// 128^2/256x128/256^2 x 1-3 blocks/CU) all land 219-280 us, floor 219 = ~630 TF.
// Binding constraint: 128-AGPR acc -> 2 waves/SIMD -> 2 blocks/CU; phase diversity
// capped; LDS ring-4 / 3-blocks all violate LDS or reg budgets. This config is the
// measured optimum of the space.
// C[row=n][col=m]. Ranked v = nm[n] - 2*dot (nf[m] deferred to merge).
// LDS XOR-swizzle: 16B chunk c of row r stored at chunk c^(r&7); staging permutes
// the per-lane SOURCE k-offset (bijection per row), frag reads XOR the chunk.
__global__ __launch_bounds__(256, 2) void gemm_topk_kernel(
    const u16* __restrict__ fvb, const u16* __restrict__ mbb,
    const float* __restrict__ nm_perm, float* __restrict__ partial)
{
  __shared__ __align__(16) u16 As[BM * BK];     // fv tile [256][64], 32 KB
  __shared__ __align__(16) u16 Bs[BN * BK];     // mb tile [128][64], 16 KB

  const int t   = threadIdx.x;
  const int l   = t & 63;
  const int w   = t >> 6;
  const int h   = l >> 5;        // half-wave
  const int c31 = l & 31;
  const int cx  = c31 & 7;       // frag-read row&7 (both As strips and Bs tiles)

  const int m0    = blockIdx.x * BM;
  const int ncoff = blockIdx.y * NPER;

  // staging: lane l covers row (base + l>>3), chunk l&7; source chunk swizzled
  const int srow_lo = l >> 3;                    // 0..7
  const int sc      = ((l & 7) ^ srow_lo) * 8;   // swizzled source k-offset (u16)

  float best[2][TOPK];
  float T[2];
  #pragma unroll
  for (int s = 0; s < 2; ++s) {
    T[s] = 3.4e38f;
    #pragma unroll
    for (int i = 0; i < TOPK; ++i) best[s][i] = 3.4e38f;
  }

  for (int nt = 0; nt < NPER / BN; ++nt) {
    const int nbase = ncoff + nt * BN;
    f32x16 acc[2][4];
    #pragma unroll
    for (int s = 0; s < 2; ++s)
      #pragma unroll
      for (int i = 0; i < 4; ++i)
        #pragma unroll
        for (int r = 0; r < 16; ++r) acc[s][i][r] = 0.0f;

    for (int kc = 0; kc < KDIM / BK; ++kc) {
      __syncthreads();
      const int kb = kc * BK + sc;
      #pragma unroll
      for (int i = 0; i < 8; ++i)
        gload_lds16(fvb + (size_t)(m0 + w * 64 + i * 8 + srow_lo) * KDIM + kb,
                    &As[(w * 64 + i * 8) * BK]);
      #pragma unroll
      for (int i = 0; i < 4; ++i)
        gload_lds16(mbb + (size_t)(nbase + w * 32 + i * 8 + srow_lo) * KDIM + kb,
                    &Bs[(w * 32 + i * 8) * BK]);
      __syncthreads();
      #pragma unroll
      for (int kk = 0; kk < 4; ++kk) {
        const int ch = ((kk * 2 + h) ^ cx) * 8;              // swizzled chunk (u16)
        bf16x8 f0 = *(const bf16x8*)&As[(w * 64 +      c31) * BK + ch];  // B-op strip 0
        bf16x8 f1 = *(const bf16x8*)&As[(w * 64 + 32 + c31) * BK + ch];  // B-op strip 1
        #pragma unroll
        for (int i = 0; i < 4; ++i) {
          bf16x8 mbf = *(const bf16x8*)&Bs[(i * 32 + c31) * BK + ch]; // A-operand (n)
          acc[0][i] = __builtin_amdgcn_mfma_f32_32x32x16_bf16(mbf, f0, acc[0][i], 0, 0, 0);
          acc[1][i] = __builtin_amdgcn_mfma_f32_32x32x16_bf16(mbf, f1, acc[1][i], 0, 0, 0);
        }
      }
    }

    // ---- register epilogue: two lists per thread; nm in permuted broadcast order ----
    #pragma unroll
    for (int i = 0; i < 4; ++i) {
      const float4* np = (const float4*)&nm_perm[(((nbase >> 5) + i) * 2 + h) * 16];
      float4 q0 = np[0], q1 = np[1], q2 = np[2], q3 = np[3];
      #pragma unroll
      for (int s = 0; s < 2; ++s) {
        float v[16];
        v[ 0] = fmaf(-2.0f, acc[s][i][ 0], q0.x);
        v[ 1] = fmaf(-2.0f, acc[s][i][ 1], q0.y);
        v[ 2] = fmaf(-2.0f, acc[s][i][ 2], q0.z);
        v[ 3] = fmaf(-2.0f, acc[s][i][ 3], q0.w);
        v[ 4] = fmaf(-2.0f, acc[s][i][ 4], q1.x);
        v[ 5] = fmaf(-2.0f, acc[s][i][ 5], q1.y);
        v[ 6] = fmaf(-2.0f, acc[s][i][ 6], q1.z);
        v[ 7] = fmaf(-2.0f, acc[s][i][ 7], q1.w);
        v[ 8] = fmaf(-2.0f, acc[s][i][ 8], q2.x);
        v[ 9] = fmaf(-2.0f, acc[s][i][ 9], q2.y);
        v[10] = fmaf(-2.0f, acc[s][i][10], q2.z);
        v[11] = fmaf(-2.0f, acc[s][i][11], q2.w);
        v[12] = fmaf(-2.0f, acc[s][i][12], q3.x);
        v[13] = fmaf(-2.0f, acc[s][i][13], q3.y);
        v[14] = fmaf(-2.0f, acc[s][i][14], q3.z);
        v[15] = fmaf(-2.0f, acc[s][i][15], q3.w);
        float bmin = 3.4e38f;
        #pragma unroll
        for (int r = 0; r < 16; ++r) bmin = fminf(bmin, v[r]);
        if (bmin < T[s]) {
          #pragma unroll
          for (int r = 0; r < 16; ++r) topk_update(v[r], best[s]);
          T[s] = best[s][TOPK - 1];
        }
      }
    }
    #pragma unroll
    for (int s = 0; s < 2; ++s)
      T[s] = fminf(best[s][TOPK - 1], __shfl_xor(best[s][TOPK - 1], 32, 64));
  }

  // merge the lane pair sharing each m-col (snapshot partner list, then insert)
  #pragma unroll
  for (int s = 0; s < 2; ++s) {
    float tmp[TOPK];
    #pragma unroll
    for (int q = 0; q < TOPK; ++q) tmp[q] = __shfl_xor(best[s][q], 32, 64);
    #pragma unroll
    for (int q = 0; q < TOPK; ++q) topk_update(tmp[q], best[s]);
    int m = m0 + w * 64 + s * 32 + c31;
    size_t base = ((size_t)blockIdx.y * M_ROWS + m) * TOPK;
    if (h == 0) {
      #pragma unroll
      for (int q = 0; q < 5; ++q) partial[base + q] = best[s][q];
    } else {
      #pragma unroll
      for (int q = 5; q < TOPK; ++q) partial[base + q] = best[s][q];
    }
  }
}

// ---- Kernel 3: merge 16 partial lists/row, sqrt, pixel scores ----
// R9: parallelized. Old version: 32 blocks (32 CUs), 144 serial 9-deep inserts
// per thread -> ~13-20 us latency-bound. Now 512 blocks x 64 thr: 4 threads per
// row (lane quarter l>>4 merges 4 sorted chunk-lists with early-break), then
// 2-step shfl_xor butterfly (32,16) merges quarters in-register; quarter 0
// writes sqrt'd list. Work/thread 144 -> ~54 inserts, CU coverage 32 -> 256.
__global__ __launch_bounds__(64) void merge_kernel(
    const float* __restrict__ partial, const float* __restrict__ nf,
    float* __restrict__ final9, float* __restrict__ out_pix)
{
  const int l   = threadIdx.x;            // 0..63
  const int row = blockIdx.x * 16 + (l & 15);
  const int q4  = l >> 4;                 // chunk quarter 0..3
  float best[TOPK];
  #pragma unroll
  for (int i = 0; i < TOPK; ++i) best[i] = 3.4e38f;
  #pragma unroll
  for (int s = 0; s < 4; ++s) {
    const float* p = &partial[((size_t)(q4 * 4 + s) * M_ROWS + row) * TOPK];
    #pragma unroll
    for (int i = 0; i < TOPK; ++i) {
      float pv = p[i];
      if (pv >= best[TOPK - 1]) break;    // chunk lists are sorted ascending
      topk_update(pv, best);
    }
  }
  // butterfly merge across the 4 quarters sharing this row
  {
    float tmp[TOPK];
    #pragma unroll
    for (int q = 0; q < TOPK; ++q) tmp[q] = __shfl_xor(best[q], 32, 64);
    #pragma unroll
    for (int q = 0; q < TOPK; ++q) topk_update(tmp[q], best);
    #pragma unroll
    for (int q = 0; q < TOPK; ++q) tmp[q] = __shfl_xor(best[q], 16, 64);
    #pragma unroll
    for (int q = 0; q < TOPK; ++q) topk_update(tmp[q], best);
  }
  if (q4 == 0) {
    float nfr = nf[row];
    float d[TOPK];
    #pragma unroll
    for (int i = 0; i < TOPK; ++i) d[i] = sqrtf(fmaxf(best[i] + nfr, 0.0f));
    out_pix[row] = d[0];
    #pragma unroll
    for (int i = 0; i < TOPK; ++i) final9[(size_t)row * TOPK + i] = d[i];
  }
}

// ---------------- Kernel 4: per-image argmax (first-max) + softmax score ----------------
__global__ __launch_bounds__(256) void img_kernel(
    const float* __restrict__ out_pix, const float* __restrict__ final9,
    const int* __restrict__ bptr, float* __restrict__ out_img)
{
  int img = blockIdx.x, t = threadIdx.x;
  float bv = -1.0f; int bi = 0;
  for (int p = t; p < 1024; p += 256) {
    float v = out_pix[img * 1024 + p];
    if (v > bv) { bv = v; bi = p; }
  }
  __shared__ float sv[256];
  __shared__ int   si[256];
  sv[t] = bv; si[t] = bi;
  __syncthreads();
  for (int off = 128; off > 0; off >>= 1) {
    if (t < off) {
      float v2 = sv[t + off]; int i2 = si[t + off];
      if (v2 > sv[t] || (v2 == sv[t] && i2 < si[t])) { sv[t] = v2; si[t] = i2; }
    }
    __syncthreads();
  }
  if (t == 0) {
    int row = img * 1024 + si[0];
    int b = bptr[0];
    float s0 = final9[(size_t)row * TOPK + 0];
    float score = s0;
    if (b > 1) {
      int bb = b < TOPK ? b : TOPK;
      float mx = s0;
      for (int i = 1; i < bb; ++i) mx = fmaxf(mx, final9[(size_t)row * TOPK + i]);
      float den = 0.0f;
      for (int i = 0; i < bb; ++i) den += expf(final9[(size_t)row * TOPK + i] - mx);
      score = s0 * (1.0f - expf(s0 - mx) / den);
    }
    out_img[img] = score;
  }
}

extern "C" void kernel_launch(void* const* d_in, const int* in_sizes, int n_in,
                              void* d_out, int out_size, void* d_ws, size_t ws_size,
                              hipStream_t stream) {
  const float* fv   = (const float*)d_in[0];
  const float* mb   = (const float*)d_in[1];
  const int*   bptr = (const int*)d_in[2];
  float* out = (float*)d_out;

  char* ws = (char*)d_ws;
  u16*   fvb     = (u16*)ws;                       // 8388608 B
  u16*   mbb     = (u16*)(ws + 8388608);           // 16777216 B
  float* nf      = (float*)(ws + 25165824);        // 32768 B
  float* nm_perm = (float*)(ws + 25198592);        // 65536 B
  float* partial = (float*)(ws + 25264128);        // 16*8192*9*4 = 4718592 B
  float* final9  = (float*)(ws + 29982720);        // 294912 B   (end ~30.3 MB)

  hipLaunchKernelGGL(prep_kernel, dim3((M_ROWS + N_ROWS) / 4), dim3(256), 0, stream,
                     fv, mb, fvb, mbb, nf, nm_perm);
  hipLaunchKernelGGL(gemm_topk_kernel, dim3(M_ROWS / BM, NCHUNKS), dim3(256), 0, stream,
                     fvb, mbb, nm_perm, partial);
  hipLaunchKernelGGL(merge_kernel, dim3(M_ROWS / 16), dim3(64), 0, stream,
                     partial, nf, final9, out);
  hipLaunchKernelGGL(img_kernel, dim3(8), dim3(256), 0, stream,
                     out, final9, bptr, out + M_ROWS);
}